// Round 1
// 1522.405 us; speedup vs baseline: 1.0697x; 1.0697x over previous
//
#include <hip/hip_runtime.h>

// AutoformerAttention on MI355X.
// Pipeline:
//   At = Wk @ Wq^T (split-bf16 MFMA)            [mean_ac needs fp32-grade accuracy]
//   P  = hs @ At   (split-bf16 MFMA, stored transposed [B,E,T])
//   V  = hs @ Wv + bv (bf16 MFMA)
//   S[b,f] = sum_e Pf * conj(HSf)  via packed complex FFT (z = P + i*hs) per (b,e)
//   mean_ac[b,:] = irfft(S)/(T*E) + (Sq+Sk+T*bq.bk)/E      (bias terms are tau-independent)
//   top-24 per b -> weights/delays; heads use set (h%8) per the reference's repeat() quirk
//   agg[b,t,e] = sum_k w[h%8,k] * V[b,(t+d)%T,e]  -> out = agg @ Wo + bo
// Workspace ~470 MB; agg aliases hs_hi (dead after the P/V GEMMs).

typedef unsigned short u16;
typedef __attribute__((ext_vector_type(8))) short short8_t;
typedef __attribute__((ext_vector_type(4))) float float4_t;

struct cplx { float x, y; };
struct __align__(8) u16x4 { u16 x, y, z, w; };

#define DEVINL static __device__ __forceinline__

DEVINL u16 bf_from_f(float x){
  unsigned u = __float_as_uint(x);
  u += 0x7fffu + ((u >> 16) & 1u);
  return (u16)(u >> 16);
}
DEVINL float f_from_bf(u16 h){ return __uint_as_float(((unsigned)h) << 16); }
DEVINL int rev12(int f){ return (int)(__brev((unsigned)f) >> 20); }

typedef const void __attribute__((address_space(1)))* gas_ptr;
typedef void __attribute__((address_space(3)))* las_ptr;
DEVINL void async16(const void* g, void* l){
  __builtin_amdgcn_global_load_lds((gas_ptr)g, (las_ptr)l, 16, 0, 0);
}

// ---------------- conversions ----------------

// fp32 -> (hi, lo) bf16 limbs, vectorized
__global__ void k_split_bf16(const float* __restrict__ x, u16* __restrict__ hi,
                             u16* __restrict__ lo, int n4){
  int i = blockIdx.x * blockDim.x + threadIdx.x;
  int stride = gridDim.x * blockDim.x;
  for (; i < n4; i += stride){
    float4 v = ((const float4*)x)[i];
    u16x4 h, l;
    h.x = bf_from_f(v.x); l.x = bf_from_f(v.x - f_from_bf(h.x));
    h.y = bf_from_f(v.y); l.y = bf_from_f(v.y - f_from_bf(h.y));
    h.z = bf_from_f(v.z); l.z = bf_from_f(v.z - f_from_bf(h.z));
    h.w = bf_from_f(v.w); l.w = bf_from_f(v.w - f_from_bf(h.w));
    ((u16x4*)hi)[i] = h; ((u16x4*)lo)[i] = l;
  }
}

// WT[n][k] = bf16(W[k][n]), 1024x1024
__global__ void k_transpose_bf16(const float* __restrict__ W, u16* __restrict__ WT){
  __shared__ float tile[32][33];
  int k0 = blockIdx.x * 32, n0 = blockIdx.y * 32;
  int x = threadIdx.x, y0 = threadIdx.y;
  for (int j = y0; j < 32; j += 8) tile[j][x] = W[(size_t)(k0 + j) * 1024 + n0 + x];
  __syncthreads();
  for (int j = y0; j < 32; j += 8) WT[(size_t)(n0 + j) * 1024 + k0 + x] = bf_from_f(tile[x][j]);
}

// [B,T,E] -> [B,E,T] fp32
__global__ void k_transpose_f32(const float* __restrict__ in, float* __restrict__ out){
  __shared__ float tile[32][33];
  int b = blockIdx.z;
  int t0 = blockIdx.x * 32, e0 = blockIdx.y * 32;
  int x = threadIdx.x, y0 = threadIdx.y;
  const float* ib = in + (size_t)b * 4194304;
  float* ob = out + (size_t)b * 4194304;
  for (int j = y0; j < 32; j += 8) tile[j][x] = ib[(size_t)(t0 + j) * 1024 + e0 + x];
  __syncthreads();
  for (int j = y0; j < 32; j += 8) ob[(size_t)(e0 + j) * 4096 + t0 + x] = tile[x][j];
}

// ---------------- GEMM (128x128 tile, 16x16x32 bf16 MFMA) ----------------
// A: [M,K] row-major bf16 (limbs). B: [N,K] row-major (i.e. math-B transposed).
// MODE 0: fp32 [M,N]; 1: P_t layout fp32 (b=n>>12, addr b*4M + m*4096 + (n&4095));
// MODE 2: bf16 [M,N] + bias[n]; 3: fp32 [M,N] + bias[n].

DEVINL void stage_tile(const u16* __restrict__ src, int ld, int row0, int kb,
                       u16* lds, int wave, int lane){
  int r = lane >> 2, c = lane & 3;
  #pragma unroll
  for (int is = wave; is < 8; is += 4){
    const u16* g = src + (size_t)(row0 + is * 16 + r) * ld + kb + c * 8;
    async16((const void*)g, (void*)(lds + is * 512));  // lds base wave-uniform, lane*16B linear
  }
}

template<int SPLIT, int MODE>
__global__ __launch_bounds__(256) void k_gemm128(
    const u16* __restrict__ Ah, const u16* __restrict__ Al,
    const u16* __restrict__ Bh, const u16* __restrict__ Bl,
    float* __restrict__ outF, u16* __restrict__ outB,
    const float* __restrict__ bias, int M, int N, int K)
{
  __shared__ u16 sAh[128 * 32];
  __shared__ u16 sBh[128 * 32];
  __shared__ u16 sAl[SPLIT ? 128 * 32 : 8];
  __shared__ u16 sBl[SPLIT ? 128 * 32 : 8];
  int tid = threadIdx.x, wave = tid >> 6, lane = tid & 63;
  int m0 = blockIdx.y * 128, n0 = blockIdx.x * 128;
  int wm = wave >> 1, wn = wave & 1;
  float4_t zero = {0.0f, 0.0f, 0.0f, 0.0f};
  float4_t acc[4][4];
  #pragma unroll
  for (int i = 0; i < 4; i++)
    #pragma unroll
    for (int j = 0; j < 4; j++) acc[i][j] = zero;

  int ar = wm * 64 + (lane & 15);
  int bc = wn * 64 + (lane & 15);
  int kq = (lane >> 4) * 8;

  for (int kb = 0; kb < K; kb += 32){
    stage_tile(Ah, K, m0, kb, sAh, wave, lane);
    stage_tile(Bh, K, n0, kb, sBh, wave, lane);
    if (SPLIT){
      stage_tile(Al, K, m0, kb, sAl, wave, lane);
      stage_tile(Bl, K, n0, kb, sBl, wave, lane);
    }
    __syncthreads();
    short8_t af[4], bfr[4], afl[4], bfl[4];
    #pragma unroll
    for (int i = 0; i < 4; i++){
      af[i]  = *(const short8_t*)(sAh + (ar + i * 16) * 32 + kq);
      bfr[i] = *(const short8_t*)(sBh + (bc + i * 16) * 32 + kq);
      if (SPLIT){
        afl[i] = *(const short8_t*)(sAl + (ar + i * 16) * 32 + kq);
        bfl[i] = *(const short8_t*)(sBl + (bc + i * 16) * 32 + kq);
      }
    }
    #pragma unroll
    for (int mi = 0; mi < 4; mi++)
      #pragma unroll
      for (int ni = 0; ni < 4; ni++){
        acc[mi][ni] = __builtin_amdgcn_mfma_f32_16x16x32_bf16(af[mi], bfr[ni], acc[mi][ni], 0, 0, 0);
        if (SPLIT){
          acc[mi][ni] = __builtin_amdgcn_mfma_f32_16x16x32_bf16(af[mi], bfl[ni], acc[mi][ni], 0, 0, 0);
          acc[mi][ni] = __builtin_amdgcn_mfma_f32_16x16x32_bf16(afl[mi], bfr[ni], acc[mi][ni], 0, 0, 0);
        }
      }
    __syncthreads();
  }

  int col = lane & 15, rq = lane >> 4;
  #pragma unroll
  for (int mi = 0; mi < 4; mi++)
    #pragma unroll
    for (int ni = 0; ni < 4; ni++){
      int gm = m0 + wm * 64 + mi * 16 + rq * 4;
      int gn = n0 + wn * 64 + ni * 16 + col;
      float4_t v = acc[mi][ni];
      #pragma unroll
      for (int r = 0; r < 4; r++){
        int row = gm + r;
        if (MODE == 0){
          outF[(size_t)row * N + gn] = v[r];
        } else if (MODE == 1){
          int bb = gn >> 12, t = gn & 4095;
          outF[(size_t)bb * 4194304 + (size_t)row * 4096 + t] = v[r];
        } else if (MODE == 2){
          outB[(size_t)row * N + gn] = bf_from_f(v[r] + bias[gn]);
        } else {
          outF[(size_t)row * N + gn] = v[r] + bias[gn];
        }
      }
    }
}

// ---------------- FFT (radix-2 DIF, in-place, output bit-reversed) ----------------

DEVINL void fft4096(cplx* z, int tid){
  for (int d = 2048; d >= 1; d >>= 1){
    __syncthreads();
    for (int j = tid; j < 2048; j += 256){
      int lo = j & (d - 1);
      int i = ((j & ~(d - 1)) << 1) | lo;
      cplx a = z[i], b = z[i + d];
      z[i].x = a.x + b.x; z[i].y = a.y + b.y;
      float tr = a.x - b.x, ti2 = a.y - b.y;
      float ang = -3.14159265358979323846f * (float)lo / (float)d;
      float s, c;
      __sincosf(ang, &s, &c);
      z[i + d].x = tr * c - ti2 * s;
      z[i + d].y = tr * s + ti2 * c;
    }
  }
  __syncthreads();
}

// forward: per (b, 8 channels): z = P + i*hs, FFT, Hermitian unpack, accumulate Pf*conj(HSf)
__global__ __launch_bounds__(256) void k_fft_fwd(const float* __restrict__ Pt,
                                                 const float* __restrict__ hsT,
                                                 float* __restrict__ S){
  __shared__ cplx z[4096];
  __shared__ cplx sacc[2049];
  int tid = threadIdx.x;
  int b = blockIdx.x >> 7;
  int ch0 = (blockIdx.x & 127) * 8;
  for (int i = tid; i < 2049; i += 256){ sacc[i].x = 0.f; sacc[i].y = 0.f; }
  for (int c = 0; c < 8; ++c){
    __syncthreads();
    size_t base = ((size_t)b * 1024 + ch0 + c) * 4096;
    for (int i = tid; i < 4096; i += 256){ z[i].x = Pt[base + i]; z[i].y = hsT[base + i]; }
    fft4096(z, tid);
    for (int f = tid; f <= 2048; f += 256){
      cplx Zp = z[rev12(f)];
      cplx Zm = z[rev12((4096 - f) & 4095)];
      float Pr = 0.5f * (Zp.x + Zm.x), Pi = 0.5f * (Zp.y - Zm.y);
      float Hr = 0.5f * (Zp.y + Zm.y), Hi = -0.5f * (Zp.x - Zm.x);
      sacc[f].x += Pr * Hr + Pi * Hi;
      sacc[f].y += Pi * Hr - Pr * Hi;
    }
  }
  __syncthreads();
  for (int f = tid; f <= 2048; f += 256){
    atomicAdd(&S[(size_t)(b * 2049 + f) * 2], sacc[f].x);
    atomicAdd(&S[(size_t)(b * 2049 + f) * 2 + 1], sacc[f].y);
  }
}

// inverse: mean_ac = Re(fft(conj(S_full)))/(T*E) + const_b/E
__global__ __launch_bounds__(256) void k_fft_inv(const float* __restrict__ S,
    const float* __restrict__ Sq, const float* __restrict__ Sk,
    const float* __restrict__ c0, float* __restrict__ mean_ac){
  __shared__ cplx z[4096];
  int b = blockIdx.x, tid = threadIdx.x;
  for (int f = tid; f < 4096; f += 256){
    if (f <= 2048){
      z[f].x = S[(size_t)(b * 2049 + f) * 2];
      z[f].y = -S[(size_t)(b * 2049 + f) * 2 + 1];
    } else {
      int g = 4096 - f;
      z[f].x = S[(size_t)(b * 2049 + g) * 2];
      z[f].y = S[(size_t)(b * 2049 + g) * 2 + 1];
    }
  }
  fft4096(z, tid);
  float constv = (Sq[b] + Sk[b] + 4096.0f * c0[0]) * (1.0f / 1024.0f);
  for (int t = tid; t < 4096; t += 256)
    mean_ac[b * 4096 + t] = z[rev12(t)].x * (1.0f / 4194304.0f) + constv;
}

// ---------------- bias-constant helpers ----------------

__global__ void k_uvc(const float* __restrict__ Wq, const float* __restrict__ Wk,
                      const float* __restrict__ bq, const float* __restrict__ bk,
                      float* __restrict__ u, float* __restrict__ w2, float* __restrict__ c0){
  int t = blockIdx.x * blockDim.x + threadIdx.x;
  if (t < 1024){
    float s = 0;
    for (int m = 0; m < 1024; ++m) s += Wq[(size_t)t * 1024 + m] * bk[m];
    u[t] = s;
  } else if (t < 2048){
    int i = t - 1024;
    float s = 0;
    for (int m = 0; m < 1024; ++m) s += Wk[(size_t)i * 1024 + m] * bq[m];
    w2[i] = s;
  } else if (t == 2048){
    float s = 0;
    for (int m = 0; m < 1024; ++m) s += bq[m] * bk[m];
    c0[0] = s;
  }
}

__global__ void k_sqsk(const float* __restrict__ hs, const float* __restrict__ u,
                       const float* __restrict__ w2, float* __restrict__ Sq,
                       float* __restrict__ Sk){
  __shared__ float r1[256], r2[256];
  int b = blockIdx.x >> 5, seg = blockIdx.x & 31;
  const float* base = hs + (size_t)b * 4194304 + (size_t)seg * 131072;
  float a1 = 0, a2 = 0;
  for (int i = threadIdx.x; i < 131072; i += 256){
    int e = i & 1023;
    float x = base[i];
    a1 += x * u[e]; a2 += x * w2[e];
  }
  r1[threadIdx.x] = a1; r2[threadIdx.x] = a2;
  __syncthreads();
  for (int s = 128; s > 0; s >>= 1){
    if (threadIdx.x < s){ r1[threadIdx.x] += r1[threadIdx.x + s]; r2[threadIdx.x] += r2[threadIdx.x + s]; }
    __syncthreads();
  }
  if (threadIdx.x == 0){ atomicAdd(&Sq[b], r1[0]); atomicAdd(&Sk[b], r2[0]); }
}

// ---------------- top-k ----------------

__global__ __launch_bounds__(256) void k_topk(const float* __restrict__ mean_ac,
                                              float* __restrict__ tv, int* __restrict__ ti){
  __shared__ float vals[4096];
  __shared__ float rv[256];
  __shared__ int ri[256];
  int b = blockIdx.x, tid = threadIdx.x;
  for (int i = tid; i < 4096; i += 256) vals[i] = mean_ac[b * 4096 + i];
  __syncthreads();
  for (int it = 0; it < 24; ++it){
    float best = -3.0e38f; int bi = 0x7fffffff;
    for (int i = tid; i < 4096; i += 256){
      float v = vals[i];
      if (v > best){ best = v; bi = i; }
    }
    rv[tid] = best; ri[tid] = bi;
    __syncthreads();
    for (int s = 128; s > 0; s >>= 1){
      if (tid < s){
        if (rv[tid + s] > rv[tid] || (rv[tid + s] == rv[tid] && ri[tid + s] < ri[tid])){
          rv[tid] = rv[tid + s]; ri[tid] = ri[tid + s];
        }
      }
      __syncthreads();
    }
    if (tid == 0){
      tv[b * 24 + it] = rv[0]; ti[b * 24 + it] = ri[0];
      vals[ri[0]] = -3.0e38f;
    }
    __syncthreads();
  }
}

// ---------------- aggregation: agg[b,t,e] = sum_k w[h%8,k] * V[b,(t+d)%T,e] ----------------
// Rewritten for L2 locality + MLP:
//  - flat grid, b = blockIdx.x & 7: under round-robin block->XCD dispatch each XCD
//    touches only V[b] (8 MB) instead of all 64 MB (old FETCH was ~8x V).
//  - 16 B loads (8 bf16/lane), 128 lanes/row; block covers 16 t's.
//  - 24 (w,d) pairs hoisted to registers; k-loop fully unrolled; bounds (256,4)
//    gives the scheduler ~128 VGPRs to keep many gathers in flight.

__global__ __launch_bounds__(256, 4) void k_aggregate(const u16* __restrict__ V,
    const float* __restrict__ tv, const int* __restrict__ ti, u16* __restrict__ agg){
  __shared__ float wv[8][24];
  __shared__ int dv[8][24];
  int tid = threadIdx.x;
  if (tid < 192){ int s = tid / 24, k = tid % 24; wv[s][k] = tv[tid]; dv[s][k] = ti[tid]; }
  __syncthreads();
  int flat = blockIdx.x;           // 2048 blocks
  int b = flat & 7;                // XCD affinity
  int t0 = (flat >> 3) * 16;
  int oct = tid & 127;             // which 8-element e-group
  int th = tid >> 7;               // t parity within the pair
  int e = oct * 8;
  int sb = (oct >> 3) & 7;         // h % 8 (h = e/64)
  const u16* Vbase = V + (size_t)b * 4194304 + e;
  u16* abase = agg + (size_t)b * 4194304 + e;

  float wk[24]; int dk[24];
  #pragma unroll
  for (int k = 0; k < 24; ++k){ wk[k] = wv[sb][k]; dk[k] = dv[sb][k]; }

  for (int tt = 0; tt < 8; ++tt){
    int t = t0 + tt * 2 + th;
    float a0 = 0, a1 = 0, a2 = 0, a3 = 0, a4 = 0, a5 = 0, a6 = 0, a7 = 0;
    #pragma unroll
    for (int k = 0; k < 24; ++k){
      int st = (t + dk[k]) & 4095;
      int4 vv = *(const int4*)(Vbase + (size_t)st * 1024);
      float w = wk[k];
      a0 += w * __uint_as_float(((unsigned)vv.x) << 16);
      a1 += w * __uint_as_float(((unsigned)vv.x) & 0xFFFF0000u);
      a2 += w * __uint_as_float(((unsigned)vv.y) << 16);
      a3 += w * __uint_as_float(((unsigned)vv.y) & 0xFFFF0000u);
      a4 += w * __uint_as_float(((unsigned)vv.z) << 16);
      a5 += w * __uint_as_float(((unsigned)vv.z) & 0xFFFF0000u);
      a6 += w * __uint_as_float(((unsigned)vv.w) << 16);
      a7 += w * __uint_as_float(((unsigned)vv.w) & 0xFFFF0000u);
    }
    int4 o;
    o.x = (int)((unsigned)bf_from_f(a0) | ((unsigned)bf_from_f(a1) << 16));
    o.y = (int)((unsigned)bf_from_f(a2) | ((unsigned)bf_from_f(a3) << 16));
    o.z = (int)((unsigned)bf_from_f(a4) | ((unsigned)bf_from_f(a5) << 16));
    o.w = (int)((unsigned)bf_from_f(a6) | ((unsigned)bf_from_f(a7) << 16));
    *(int4*)(abase + (size_t)t * 1024) = o;
  }
}

// ---------------- launch ----------------

extern "C" void kernel_launch(void* const* d_in, const int* in_sizes, int n_in,
                              void* d_out, int out_size, void* d_ws, size_t ws_size,
                              hipStream_t stream){
  const float* hs = (const float*)d_in[0];
  const float* Wq = (const float*)d_in[1];
  const float* bq = (const float*)d_in[2];
  const float* Wk = (const float*)d_in[3];
  const float* bk = (const float*)d_in[4];
  const float* Wv = (const float*)d_in[5];
  const float* bv = (const float*)d_in[6];
  const float* Wo = (const float*)d_in[7];
  const float* bo = (const float*)d_in[8];

  char* ws = (char*)d_ws;
  const size_t MB = 1024ull * 1024ull;
  u16* hs_hi = (u16*)(ws);                 // 64MB; reused as agg after P/V GEMMs
  u16* hs_lo = (u16*)(ws + 64 * MB);       // 64MB
  float* Pt  = (float*)(ws + 128 * MB);    // 128MB  [B,E,T]
  float* hsT = (float*)(ws + 256 * MB);    // 128MB  [B,E,T]
  u16* Vb    = (u16*)(ws + 384 * MB);      // 64MB bf16 [B,T,E]
  char* sm   = ws + 448 * MB;
  u16* Wq_hi = (u16*)(sm + 0 * MB);
  u16* Wq_lo = (u16*)(sm + 2 * MB);
  u16* Wk_hi = (u16*)(sm + 4 * MB);
  u16* Wk_lo = (u16*)(sm + 6 * MB);
  u16* WvT   = (u16*)(sm + 8 * MB);
  u16* WoT   = (u16*)(sm + 10 * MB);
  float* At  = (float*)(sm + 12 * MB);     // 4MB fp32
  u16* At_hi = (u16*)(sm + 16 * MB);
  u16* At_lo = (u16*)(sm + 18 * MB);
  float* S   = (float*)(sm + 20 * MB);     // 8 x 2049 cplx
  float* mean_ac = (float*)(sm + 21 * MB);
  float* uu  = (float*)(sm + 22 * MB);
  float* w2  = (float*)(sm + 22 * MB + 8192);
  float* c0  = (float*)(sm + 22 * MB + 16384);
  float* Sq  = (float*)(sm + 22 * MB + 16640);
  float* Sk  = (float*)(sm + 22 * MB + 16896);
  float* tv  = (float*)(sm + 22 * MB + 17152);
  int*   ti  = (int*)(sm + 22 * MB + 18176);
  u16* agg   = hs_hi;

  hipMemsetAsync(S, 0, 8 * 2049 * 2 * sizeof(float), stream);
  hipMemsetAsync(Sq, 0, 8 * sizeof(float), stream);
  hipMemsetAsync(Sk, 0, 8 * sizeof(float), stream);

  k_split_bf16<<<8192, 256, 0, stream>>>(hs, hs_hi, hs_lo, 8388608);
  k_split_bf16<<<1024, 256, 0, stream>>>(Wq, Wq_hi, Wq_lo, 262144);
  k_split_bf16<<<1024, 256, 0, stream>>>(Wk, Wk_hi, Wk_lo, 262144);
  k_transpose_bf16<<<dim3(32, 32), dim3(32, 8), 0, stream>>>(Wv, WvT);
  k_transpose_bf16<<<dim3(32, 32), dim3(32, 8), 0, stream>>>(Wo, WoT);
  k_uvc<<<9, 256, 0, stream>>>(Wq, Wk, bq, bk, uu, w2, c0);
  k_sqsk<<<256, 256, 0, stream>>>(hs, uu, w2, Sq, Sk);
  k_transpose_f32<<<dim3(128, 32, 8), dim3(32, 8), 0, stream>>>(hs, hsT);

  // At[e,k] = sum_m Wk[e,m] * Wq[k,m]  (= (Wq Wk^T)^T), split-bf16
  k_gemm128<1, 0><<<dim3(8, 8), 256, 0, stream>>>(Wk_hi, Wk_lo, Wq_hi, Wq_lo,
                                                  At, nullptr, nullptr, 1024, 1024, 1024);
  k_split_bf16<<<1024, 256, 0, stream>>>(At, At_hi, At_lo, 262144);
  // P^T[e, t'] = sum_k At[e,k] * hs[t',k]  -> stored [B,E,T]
  k_gemm128<1, 1><<<dim3(256, 8), 256, 0, stream>>>(At_hi, At_lo, hs_hi, hs_lo,
                                                    Pt, nullptr, nullptr, 1024, 32768, 1024);
  // V = hs @ Wv + bv (bf16)
  k_gemm128<0, 2><<<dim3(8, 256), 256, 0, stream>>>(hs_hi, nullptr, WvT, nullptr,
                                                    nullptr, Vb, bv, 32768, 1024, 1024);

  k_fft_fwd<<<1024, 256, 0, stream>>>(Pt, hsT, S);
  k_fft_inv<<<8, 256, 0, stream>>>(S, Sq, Sk, c0, mean_ac);
  k_topk<<<8, 256, 0, stream>>>(mean_ac, tv, ti);
  k_aggregate<<<2048, 256, 0, stream>>>(Vb, tv, ti, agg);
  // out = agg @ Wo + bo (fp32 out)
  k_gemm128<0, 3><<<dim3(8, 256), 256, 0, stream>>>(agg, nullptr, WoT, nullptr,
                                                    (float*)d_out, nullptr, bo, 32768, 1024, 1024);
}

// Round 2
// 1421.427 us; speedup vs baseline: 1.1456x; 1.0710x over previous
//
#include <hip/hip_runtime.h>

// AutoformerAttention on MI355X.
// Pipeline:
//   At = Wk @ Wq^T (split-bf16 MFMA)            [mean_ac needs fp32-grade accuracy]
//   P  = hs @ At   (split-bf16 MFMA, stored transposed [B,E,T])
//   V  = hs @ Wv + bv (bf16 MFMA)
//   S[b,pair] = sum_e Pf * conj(HSf) via packed complex FFT (z = P + i*hs) per (b,e),
//     computed ENTIRELY in the bit-reversed (scrambled) domain: the Hermitian partner
//     of DIF position p is the mirror within its leading-bit block (q = 3*2^k-1-p),
//     so the unpack is stride-1 runs (no rev12 scatter). S stored pair-indexed.
//   mean_ac[b,:] = DIT-FFT (scrambled in -> natural out) of conj(S) /(T*E) + const/E
//   top-24 per b -> weights/delays; heads use set (h%8) per the reference's repeat() quirk
//   agg[b,t,e] = sum_k w[h%8,k] * V[b,(t+d)%T,e]  -> out = agg @ Wo + bo
// Workspace ~470 MB; agg aliases hs_hi (dead after the P/V GEMMs).

typedef unsigned short u16;
typedef __attribute__((ext_vector_type(8))) short short8_t;
typedef __attribute__((ext_vector_type(4))) float float4_t;

struct cplx { float x, y; };
struct __align__(8) u16x4 { u16 x, y, z, w; };

#define DEVINL static __device__ __forceinline__

DEVINL u16 bf_from_f(float x){
  unsigned u = __float_as_uint(x);
  u += 0x7fffu + ((u >> 16) & 1u);
  return (u16)(u >> 16);
}
DEVINL float f_from_bf(u16 h){ return __uint_as_float(((unsigned)h) << 16); }

typedef const void __attribute__((address_space(1)))* gas_ptr;
typedef void __attribute__((address_space(3)))* las_ptr;
DEVINL void async16(const void* g, void* l){
  __builtin_amdgcn_global_load_lds((gas_ptr)g, (las_ptr)l, 16, 0, 0);
}

// ---------------- conversions ----------------

// fp32 -> (hi, lo) bf16 limbs, vectorized
__global__ void k_split_bf16(const float* __restrict__ x, u16* __restrict__ hi,
                             u16* __restrict__ lo, int n4){
  int i = blockIdx.x * blockDim.x + threadIdx.x;
  int stride = gridDim.x * blockDim.x;
  for (; i < n4; i += stride){
    float4 v = ((const float4*)x)[i];
    u16x4 h, l;
    h.x = bf_from_f(v.x); l.x = bf_from_f(v.x - f_from_bf(h.x));
    h.y = bf_from_f(v.y); l.y = bf_from_f(v.y - f_from_bf(h.y));
    h.z = bf_from_f(v.z); l.z = bf_from_f(v.z - f_from_bf(h.z));
    h.w = bf_from_f(v.w); l.w = bf_from_f(v.w - f_from_bf(h.w));
    ((u16x4*)hi)[i] = h; ((u16x4*)lo)[i] = l;
  }
}

// WT[n][k] = bf16(W[k][n]), 1024x1024
__global__ void k_transpose_bf16(const float* __restrict__ W, u16* __restrict__ WT){
  __shared__ float tile[32][33];
  int k0 = blockIdx.x * 32, n0 = blockIdx.y * 32;
  int x = threadIdx.x, y0 = threadIdx.y;
  for (int j = y0; j < 32; j += 8) tile[j][x] = W[(size_t)(k0 + j) * 1024 + n0 + x];
  __syncthreads();
  for (int j = y0; j < 32; j += 8) WT[(size_t)(n0 + j) * 1024 + k0 + x] = bf_from_f(tile[x][j]);
}

// [B,T,E] -> [B,E,T] fp32
__global__ void k_transpose_f32(const float* __restrict__ in, float* __restrict__ out){
  __shared__ float tile[32][33];
  int b = blockIdx.z;
  int t0 = blockIdx.x * 32, e0 = blockIdx.y * 32;
  int x = threadIdx.x, y0 = threadIdx.y;
  const float* ib = in + (size_t)b * 4194304;
  float* ob = out + (size_t)b * 4194304;
  for (int j = y0; j < 32; j += 8) tile[j][x] = ib[(size_t)(t0 + j) * 1024 + e0 + x];
  __syncthreads();
  for (int j = y0; j < 32; j += 8) ob[(size_t)(e0 + j) * 4096 + t0 + x] = tile[x][j];
}

// ---------------- GEMM (128x128 tile, 16x16x32 bf16 MFMA) ----------------
// A: [M,K] row-major bf16 (limbs). B: [N,K] row-major (i.e. math-B transposed).
// MODE 0: fp32 [M,N]; 1: P_t layout fp32 (b=n>>12, addr b*4M + m*4096 + (n&4095));
// MODE 2: bf16 [M,N] + bias[n]; 3: fp32 [M,N] + bias[n].

DEVINL void stage_tile(const u16* __restrict__ src, int ld, int row0, int kb,
                       u16* lds, int wave, int lane){
  int r = lane >> 2, c = lane & 3;
  #pragma unroll
  for (int is = wave; is < 8; is += 4){
    const u16* g = src + (size_t)(row0 + is * 16 + r) * ld + kb + c * 8;
    async16((const void*)g, (void*)(lds + is * 512));  // lds base wave-uniform, lane*16B linear
  }
}

template<int SPLIT, int MODE>
__global__ __launch_bounds__(256) void k_gemm128(
    const u16* __restrict__ Ah, const u16* __restrict__ Al,
    const u16* __restrict__ Bh, const u16* __restrict__ Bl,
    float* __restrict__ outF, u16* __restrict__ outB,
    const float* __restrict__ bias, int M, int N, int K)
{
  __shared__ u16 sAh[128 * 32];
  __shared__ u16 sBh[128 * 32];
  __shared__ u16 sAl[SPLIT ? 128 * 32 : 8];
  __shared__ u16 sBl[SPLIT ? 128 * 32 : 8];
  int tid = threadIdx.x, wave = tid >> 6, lane = tid & 63;
  int m0 = blockIdx.y * 128, n0 = blockIdx.x * 128;
  int wm = wave >> 1, wn = wave & 1;
  float4_t zero = {0.0f, 0.0f, 0.0f, 0.0f};
  float4_t acc[4][4];
  #pragma unroll
  for (int i = 0; i < 4; i++)
    #pragma unroll
    for (int j = 0; j < 4; j++) acc[i][j] = zero;

  int ar = wm * 64 + (lane & 15);
  int bc = wn * 64 + (lane & 15);
  int kq = (lane >> 4) * 8;

  for (int kb = 0; kb < K; kb += 32){
    stage_tile(Ah, K, m0, kb, sAh, wave, lane);
    stage_tile(Bh, K, n0, kb, sBh, wave, lane);
    if (SPLIT){
      stage_tile(Al, K, m0, kb, sAl, wave, lane);
      stage_tile(Bl, K, n0, kb, sBl, wave, lane);
    }
    __syncthreads();
    short8_t af[4], bfr[4], afl[4], bfl[4];
    #pragma unroll
    for (int i = 0; i < 4; i++){
      af[i]  = *(const short8_t*)(sAh + (ar + i * 16) * 32 + kq);
      bfr[i] = *(const short8_t*)(sBh + (bc + i * 16) * 32 + kq);
      if (SPLIT){
        afl[i] = *(const short8_t*)(sAl + (ar + i * 16) * 32 + kq);
        bfl[i] = *(const short8_t*)(sBl + (bc + i * 16) * 32 + kq);
      }
    }
    #pragma unroll
    for (int mi = 0; mi < 4; mi++)
      #pragma unroll
      for (int ni = 0; ni < 4; ni++){
        acc[mi][ni] = __builtin_amdgcn_mfma_f32_16x16x32_bf16(af[mi], bfr[ni], acc[mi][ni], 0, 0, 0);
        if (SPLIT){
          acc[mi][ni] = __builtin_amdgcn_mfma_f32_16x16x32_bf16(af[mi], bfl[ni], acc[mi][ni], 0, 0, 0);
          acc[mi][ni] = __builtin_amdgcn_mfma_f32_16x16x32_bf16(afl[mi], bfr[ni], acc[mi][ni], 0, 0, 0);
        }
      }
    __syncthreads();
  }

  int col = lane & 15, rq = lane >> 4;
  #pragma unroll
  for (int mi = 0; mi < 4; mi++)
    #pragma unroll
    for (int ni = 0; ni < 4; ni++){
      int gm = m0 + wm * 64 + mi * 16 + rq * 4;
      int gn = n0 + wn * 64 + ni * 16 + col;
      float4_t v = acc[mi][ni];
      #pragma unroll
      for (int r = 0; r < 4; r++){
        int row = gm + r;
        if (MODE == 0){
          outF[(size_t)row * N + gn] = v[r];
        } else if (MODE == 1){
          int bb = gn >> 12, t = gn & 4095;
          outF[(size_t)bb * 4194304 + (size_t)row * 4096 + t] = v[r];
        } else if (MODE == 2){
          outB[(size_t)row * N + gn] = bf_from_f(v[r] + bias[gn]);
        } else {
          outF[(size_t)row * N + gn] = v[r] + bias[gn];
        }
      }
    }
}

// ---------------- FFT forward (fused radix-4 DIF, SoA + pad, scrambled-domain unpack) ----
// LDS layout: zr/zi padded 1-per-8 floats -> all 6 fused passes and the pair-unpack are
// ~2-way bank access (free). No bit-reversal is ever materialized: DIF position p holds
// freq rev12(p); the Hermitian partner (freq -f) sits at q = mirror of p within its
// leading-bit block [2^k, 2^{k+1}): q = 3*2^k - 1 - p. Selfs: p=0 (f=0), p=1 (f=2048).
// S layout per b: slot 0 = self p0, slot 1 = self p1, slot 2+idx = pair idx (idx 0..2046,
// m = idx+1, e = floor(log2 m), p = m + 2^e). 2049 slots * 2 floats, matches old size.

#define FPAD(i) ((i) + ((i) >> 3))

__global__ __launch_bounds__(256) void k_fft_fwd(const float* __restrict__ Pt,
                                                 const float* __restrict__ hsT,
                                                 float* __restrict__ S){
  __shared__ float zr[4608];
  __shared__ float zi[4608];
  int tid = threadIdx.x;
  int b = blockIdx.x >> 7;
  int ch0 = (blockIdx.x & 127) * 8;
  float Gre[8], Gim[8];
  #pragma unroll
  for (int j = 0; j < 8; ++j){ Gre[j] = 0.f; Gim[j] = 0.f; }
  float g0 = 0.f, g1 = 0.f;

  for (int c = 0; c < 8; ++c){
    __syncthreads();  // previous channel's unpack reads complete before overwrite
    size_t base = ((size_t)b * 1024 + ch0 + c) * 4096;
    for (int i = tid; i < 4096; i += 256){
      zr[FPAD(i)] = Pt[base + i];
      zi[FPAD(i)] = hsT[base + i];
    }
    // 6 fused radix-4 passes == 12 radix-2 DIF stages (identical math, bit-reversed out)
    for (int h = 1024; h >= 1; h >>= 2){
      __syncthreads();
      float wsc = -3.14159265358979323846f / (float)(2 * h);
      for (int g = tid; g < 1024; g += 256){
        int lo = g & (h - 1);
        int i0 = ((g - lo) << 2) + lo;
        int j0 = FPAD(i0), j1 = FPAD(i0 + h), j2 = FPAD(i0 + 2 * h), j3 = FPAD(i0 + 3 * h);
        float x0 = zr[j0], y0 = zi[j0];
        float x1 = zr[j1], y1 = zi[j1];
        float x2 = zr[j2], y2 = zi[j2];
        float x3 = zr[j3], y3 = zi[j3];
        float s, co;
        __sincosf(wsc * (float)lo, &s, &co);
        // stage 2h: (a0,a2) twiddle W = co + i s; (a1,a3) twiddle -i*W
        float b0x = x0 + x2, b0y = y0 + y2;
        float t2x = x0 - x2, t2y = y0 - y2;
        float b2x = t2x * co - t2y * s, b2y = t2x * s + t2y * co;
        float b1x = x1 + x3, b1y = y1 + y3;
        float t3x = x1 - x3, t3y = y1 - y3;
        float b3x = t3x * s + t3y * co, b3y = t3y * s - t3x * co;
        // stage h: twiddle V = W^2 for both pairs
        float vc = co * co - s * s, vs = 2.0f * co * s;
        float d1x = b0x - b1x, d1y = b0y - b1y;
        float d3x = b2x - b3x, d3y = b2y - b3y;
        zr[j0] = b0x + b1x;            zi[j0] = b0y + b1y;
        zr[j1] = d1x * vc - d1y * vs;  zi[j1] = d1x * vs + d1y * vc;
        zr[j2] = b2x + b3x;            zi[j2] = b2y + b3y;
        zr[j3] = d3x * vc - d3y * vs;  zi[j3] = d3x * vs + d3y * vc;
      }
    }
    __syncthreads();
    // scrambled-domain Hermitian-pair unpack, G accumulated in registers.
    // Re G[f] = Im(z[p]*z[q])/2 ; Im G[f] = (|z[p]|^2 - |z[q]|^2)/4  (f = rev12(p))
    #pragma unroll
    for (int j = 0; j < 8; ++j){
      int idx = tid + (j << 8);
      if (idx < 2047){
        int m = idx + 1;
        int e = 31 - __clz(m);
        int p = m + (1 << e);
        int q = (3 << (e + 1)) - 1 - p;
        int ip = FPAD(p), iq = FPAD(q);
        float xa = zr[ip], ya = zi[ip];
        float xb = zr[iq], yb = zi[iq];
        Gre[j] += 0.5f * (xa * yb + ya * xb);
        Gim[j] += 0.25f * ((xa * xa + ya * ya) - (xb * xb + yb * yb));
      }
    }
    if (tid == 0){
      g0 += zr[0] * zi[0];                  // f=0:    G = P^ * H^ (both real)
      g1 += zr[FPAD(1)] * zi[FPAD(1)];      // f=2048: same (Nyquist real)
    }
  }

  float* Sb = S + (size_t)b * 2049 * 2;
  #pragma unroll
  for (int j = 0; j < 8; ++j){
    int idx = tid + (j << 8);
    if (idx < 2047){
      atomicAdd(&Sb[(2 + idx) * 2], Gre[j]);
      atomicAdd(&Sb[(2 + idx) * 2 + 1], Gim[j]);
    }
  }
  if (tid == 0){ atomicAdd(&Sb[0], g0); atomicAdd(&Sb[2], g1); }
}

// inverse: mean_ac = Re(DIT_FFT(conj(S_scrambled)))/(T*E) + const_b/E
// DIT consumes the bit-reversed (pair-indexed) S directly, outputs natural order.
__global__ __launch_bounds__(256) void k_fft_inv(const float* __restrict__ S,
    const float* __restrict__ Sq, const float* __restrict__ Sk,
    const float* __restrict__ c0, float* __restrict__ mean_ac){
  __shared__ cplx z[4096];
  int b = blockIdx.x, tid = threadIdx.x;
  const float* Sb = S + (size_t)b * 2049 * 2;
  #pragma unroll
  for (int j = 0; j < 8; ++j){
    int idx = tid + (j << 8);
    if (idx < 2047){
      int m = idx + 1;
      int e = 31 - __clz(m);
      int p = m + (1 << e);
      int q = (3 << (e + 1)) - 1 - p;
      float re = Sb[(2 + idx) * 2], im = Sb[(2 + idx) * 2 + 1];
      z[p].x = re; z[p].y = -im;   // conj(G) at position p
      z[q].x = re; z[q].y = im;    // conj(G[-f]) = conj(conj(G[f])) = G[f]
    }
  }
  if (tid == 0){
    z[0].x = Sb[0]; z[0].y = -Sb[1];
    z[1].x = Sb[2]; z[1].y = -Sb[3];
  }
  // DIT radix-2: bit-reversed input -> natural output, forward-DFT twiddles
  for (int d = 1; d <= 2048; d <<= 1){
    __syncthreads();
    for (int j = tid; j < 2048; j += 256){
      int lo = j & (d - 1);
      int i = ((j & ~(d - 1)) << 1) | lo;
      float ang = -3.14159265358979323846f * (float)lo / (float)d;
      float s, co;
      __sincosf(ang, &s, &co);
      cplx av = z[i], bv = z[i + d];
      float tx = bv.x * co - bv.y * s;
      float ty = bv.x * s + bv.y * co;
      z[i].x = av.x + tx;     z[i].y = av.y + ty;
      z[i + d].x = av.x - tx; z[i + d].y = av.y - ty;
    }
  }
  __syncthreads();
  float constv = (Sq[b] + Sk[b] + 4096.0f * c0[0]) * (1.0f / 1024.0f);
  for (int t = tid; t < 4096; t += 256)
    mean_ac[b * 4096 + t] = z[t].x * (1.0f / 4194304.0f) + constv;
}

// ---------------- bias-constant helpers ----------------

__global__ void k_uvc(const float* __restrict__ Wq, const float* __restrict__ Wk,
                      const float* __restrict__ bq, const float* __restrict__ bk,
                      float* __restrict__ u, float* __restrict__ w2, float* __restrict__ c0){
  int t = blockIdx.x * blockDim.x + threadIdx.x;
  if (t < 1024){
    float s = 0;
    for (int m = 0; m < 1024; ++m) s += Wq[(size_t)t * 1024 + m] * bk[m];
    u[t] = s;
  } else if (t < 2048){
    int i = t - 1024;
    float s = 0;
    for (int m = 0; m < 1024; ++m) s += Wk[(size_t)i * 1024 + m] * bq[m];
    w2[i] = s;
  } else if (t == 2048){
    float s = 0;
    for (int m = 0; m < 1024; ++m) s += bq[m] * bk[m];
    c0[0] = s;
  }
}

__global__ void k_sqsk(const float* __restrict__ hs, const float* __restrict__ u,
                       const float* __restrict__ w2, float* __restrict__ Sq,
                       float* __restrict__ Sk){
  __shared__ float r1[256], r2[256];
  int b = blockIdx.x >> 5, seg = blockIdx.x & 31;
  const float* base = hs + (size_t)b * 4194304 + (size_t)seg * 131072;
  float a1 = 0, a2 = 0;
  for (int i = threadIdx.x; i < 131072; i += 256){
    int e = i & 1023;
    float x = base[i];
    a1 += x * u[e]; a2 += x * w2[e];
  }
  r1[threadIdx.x] = a1; r2[threadIdx.x] = a2;
  __syncthreads();
  for (int s = 128; s > 0; s >>= 1){
    if (threadIdx.x < s){ r1[threadIdx.x] += r1[threadIdx.x + s]; r2[threadIdx.x] += r2[threadIdx.x + s]; }
    __syncthreads();
  }
  if (threadIdx.x == 0){ atomicAdd(&Sq[b], r1[0]); atomicAdd(&Sk[b], r2[0]); }
}

// ---------------- top-k ----------------

__global__ __launch_bounds__(256) void k_topk(const float* __restrict__ mean_ac,
                                              float* __restrict__ tv, int* __restrict__ ti){
  __shared__ float vals[4096];
  __shared__ float rv[256];
  __shared__ int ri[256];
  int b = blockIdx.x, tid = threadIdx.x;
  for (int i = tid; i < 4096; i += 256) vals[i] = mean_ac[b * 4096 + i];
  __syncthreads();
  for (int it = 0; it < 24; ++it){
    float best = -3.0e38f; int bi = 0x7fffffff;
    for (int i = tid; i < 4096; i += 256){
      float v = vals[i];
      if (v > best){ best = v; bi = i; }
    }
    rv[tid] = best; ri[tid] = bi;
    __syncthreads();
    for (int s = 128; s > 0; s >>= 1){
      if (tid < s){
        if (rv[tid + s] > rv[tid] || (rv[tid + s] == rv[tid] && ri[tid + s] < ri[tid])){
          rv[tid] = rv[tid + s]; ri[tid] = ri[tid + s];
        }
      }
      __syncthreads();
    }
    if (tid == 0){
      tv[b * 24 + it] = rv[0]; ti[b * 24 + it] = ri[0];
      vals[ri[0]] = -3.0e38f;
    }
    __syncthreads();
  }
}

// ---------------- aggregation: agg[b,t,e] = sum_k w[h%8,k] * V[b,(t+d)%T,e] ----------------
// flat grid, b = blockIdx.x & 7 (XCD affinity: each XCD touches only V[b] = 8 MB);
// 16 B loads; (w,d) pairs in registers; k-loop fully unrolled.

__global__ __launch_bounds__(256, 4) void k_aggregate(const u16* __restrict__ V,
    const float* __restrict__ tv, const int* __restrict__ ti, u16* __restrict__ agg){
  __shared__ float wv[8][24];
  __shared__ int dv[8][24];
  int tid = threadIdx.x;
  if (tid < 192){ int s = tid / 24, k = tid % 24; wv[s][k] = tv[tid]; dv[s][k] = ti[tid]; }
  __syncthreads();
  int flat = blockIdx.x;           // 2048 blocks
  int b = flat & 7;                // XCD affinity
  int t0 = (flat >> 3) * 16;
  int oct = tid & 127;             // which 8-element e-group
  int th = tid >> 7;               // t parity within the pair
  int e = oct * 8;
  int sb = (oct >> 3) & 7;         // h % 8 (h = e/64)
  const u16* Vbase = V + (size_t)b * 4194304 + e;
  u16* abase = agg + (size_t)b * 4194304 + e;

  float wk[24]; int dk[24];
  #pragma unroll
  for (int k = 0; k < 24; ++k){ wk[k] = wv[sb][k]; dk[k] = dv[sb][k]; }

  for (int tt = 0; tt < 8; ++tt){
    int t = t0 + tt * 2 + th;
    float a0 = 0, a1 = 0, a2 = 0, a3 = 0, a4 = 0, a5 = 0, a6 = 0, a7 = 0;
    #pragma unroll
    for (int k = 0; k < 24; ++k){
      int st = (t + dk[k]) & 4095;
      int4 vv = *(const int4*)(Vbase + (size_t)st * 1024);
      float w = wk[k];
      a0 += w * __uint_as_float(((unsigned)vv.x) << 16);
      a1 += w * __uint_as_float(((unsigned)vv.x) & 0xFFFF0000u);
      a2 += w * __uint_as_float(((unsigned)vv.y) << 16);
      a3 += w * __uint_as_float(((unsigned)vv.y) & 0xFFFF0000u);
      a4 += w * __uint_as_float(((unsigned)vv.z) << 16);
      a5 += w * __uint_as_float(((unsigned)vv.z) & 0xFFFF0000u);
      a6 += w * __uint_as_float(((unsigned)vv.w) << 16);
      a7 += w * __uint_as_float(((unsigned)vv.w) & 0xFFFF0000u);
    }
    int4 o;
    o.x = (int)((unsigned)bf_from_f(a0) | ((unsigned)bf_from_f(a1) << 16));
    o.y = (int)((unsigned)bf_from_f(a2) | ((unsigned)bf_from_f(a3) << 16));
    o.z = (int)((unsigned)bf_from_f(a4) | ((unsigned)bf_from_f(a5) << 16));
    o.w = (int)((unsigned)bf_from_f(a6) | ((unsigned)bf_from_f(a7) << 16));
    *(int4*)(abase + (size_t)t * 1024) = o;
  }
}

// ---------------- launch ----------------

extern "C" void kernel_launch(void* const* d_in, const int* in_sizes, int n_in,
                              void* d_out, int out_size, void* d_ws, size_t ws_size,
                              hipStream_t stream){
  const float* hs = (const float*)d_in[0];
  const float* Wq = (const float*)d_in[1];
  const float* bq = (const float*)d_in[2];
  const float* Wk = (const float*)d_in[3];
  const float* bk = (const float*)d_in[4];
  const float* Wv = (const float*)d_in[5];
  const float* bv = (const float*)d_in[6];
  const float* Wo = (const float*)d_in[7];
  const float* bo = (const float*)d_in[8];

  char* ws = (char*)d_ws;
  const size_t MB = 1024ull * 1024ull;
  u16* hs_hi = (u16*)(ws);                 // 64MB; reused as agg after P/V GEMMs
  u16* hs_lo = (u16*)(ws + 64 * MB);       // 64MB
  float* Pt  = (float*)(ws + 128 * MB);    // 128MB  [B,E,T]
  float* hsT = (float*)(ws + 256 * MB);    // 128MB  [B,E,T]
  u16* Vb    = (u16*)(ws + 384 * MB);      // 64MB bf16 [B,T,E]
  char* sm   = ws + 448 * MB;
  u16* Wq_hi = (u16*)(sm + 0 * MB);
  u16* Wq_lo = (u16*)(sm + 2 * MB);
  u16* Wk_hi = (u16*)(sm + 4 * MB);
  u16* Wk_lo = (u16*)(sm + 6 * MB);
  u16* WvT   = (u16*)(sm + 8 * MB);
  u16* WoT   = (u16*)(sm + 10 * MB);
  float* At  = (float*)(sm + 12 * MB);     // 4MB fp32
  u16* At_hi = (u16*)(sm + 16 * MB);
  u16* At_lo = (u16*)(sm + 18 * MB);
  float* S   = (float*)(sm + 20 * MB);     // 8 x 2049 pair-slots x 2 floats
  float* mean_ac = (float*)(sm + 21 * MB);
  float* uu  = (float*)(sm + 22 * MB);
  float* w2  = (float*)(sm + 22 * MB + 8192);
  float* c0  = (float*)(sm + 22 * MB + 16384);
  float* Sq  = (float*)(sm + 22 * MB + 16640);
  float* Sk  = (float*)(sm + 22 * MB + 16896);
  float* tv  = (float*)(sm + 22 * MB + 17152);
  int*   ti  = (int*)(sm + 22 * MB + 18176);
  u16* agg   = hs_hi;

  hipMemsetAsync(S, 0, 8 * 2049 * 2 * sizeof(float), stream);
  hipMemsetAsync(Sq, 0, 8 * sizeof(float), stream);
  hipMemsetAsync(Sk, 0, 8 * sizeof(float), stream);

  k_split_bf16<<<8192, 256, 0, stream>>>(hs, hs_hi, hs_lo, 8388608);
  k_split_bf16<<<1024, 256, 0, stream>>>(Wq, Wq_hi, Wq_lo, 262144);
  k_split_bf16<<<1024, 256, 0, stream>>>(Wk, Wk_hi, Wk_lo, 262144);
  k_transpose_bf16<<<dim3(32, 32), dim3(32, 8), 0, stream>>>(Wv, WvT);
  k_transpose_bf16<<<dim3(32, 32), dim3(32, 8), 0, stream>>>(Wo, WoT);
  k_uvc<<<9, 256, 0, stream>>>(Wq, Wk, bq, bk, uu, w2, c0);
  k_sqsk<<<256, 256, 0, stream>>>(hs, uu, w2, Sq, Sk);
  k_transpose_f32<<<dim3(128, 32, 8), dim3(32, 8), 0, stream>>>(hs, hsT);

  // At[e,k] = sum_m Wk[e,m] * Wq[k,m]  (= (Wq Wk^T)^T), split-bf16
  k_gemm128<1, 0><<<dim3(8, 8), 256, 0, stream>>>(Wk_hi, Wk_lo, Wq_hi, Wq_lo,
                                                  At, nullptr, nullptr, 1024, 1024, 1024);
  k_split_bf16<<<1024, 256, 0, stream>>>(At, At_hi, At_lo, 262144);
  // P^T[e, t'] = sum_k At[e,k] * hs[t',k]  -> stored [B,E,T]
  k_gemm128<1, 1><<<dim3(256, 8), 256, 0, stream>>>(At_hi, At_lo, hs_hi, hs_lo,
                                                    Pt, nullptr, nullptr, 1024, 32768, 1024);
  // V = hs @ Wv + bv (bf16)
  k_gemm128<0, 2><<<dim3(8, 256), 256, 0, stream>>>(hs_hi, nullptr, WvT, nullptr,
                                                    nullptr, Vb, bv, 32768, 1024, 1024);

  k_fft_fwd<<<1024, 256, 0, stream>>>(Pt, hsT, S);
  k_fft_inv<<<8, 256, 0, stream>>>(S, Sq, Sk, c0, mean_ac);
  k_topk<<<8, 256, 0, stream>>>(mean_ac, tv, ti);
  k_aggregate<<<2048, 256, 0, stream>>>(Vb, tv, ti, agg);
  // out = agg @ Wo + bo (fp32 out)
  k_gemm128<0, 3><<<dim3(8, 256), 256, 0, stream>>>(agg, nullptr, WoT, nullptr,
                                                    (float*)d_out, nullptr, bo, 32768, 1024, 1024);
}